// Round 1
// baseline (142.797 us; speedup 1.0000x reference)
//
#include <hip/hip_runtime.h>

#define BB 4
#define NN 2048
#define DD 128
#define HH 4
#define HD 32
#define RLL 4
#define BH (BB*HH)

typedef __attribute__((ext_vector_type(8))) short short8;
typedef __attribute__((ext_vector_type(4))) float f32x4;

static __device__ __forceinline__ short f2bf(float f) {
  unsigned u = __builtin_bit_cast(unsigned, f);
  u = (u + 0x7FFFu + ((u >> 16) & 1u)) >> 16;
  return (short)u;
}
static __device__ __forceinline__ float bf2f(short s) {
  unsigned u = ((unsigned)(unsigned short)s) << 16;
  return __builtin_bit_cast(float, u);
}

// K1: fr = h @ Wr.T  -> Vt[bh][d][j] (bf16 bits), V transposed for MFMA B-frag loads
__global__ __launch_bounds__(256) void k1_proj(
    const float* __restrict__ h, const float* __restrict__ Wr,
    short* __restrict__ Vt) {
  __shared__ float hs[16 * DD];
  const int t = threadIdx.x;
  const int rbase = blockIdx.x * 16;
  {
    const float4* src = (const float4*)(h + (size_t)rbase * DD);
    float4* dst = (float4*)hs;
#pragma unroll
    for (int i = 0; i < 2; ++i) dst[t + 256 * i] = src[t + 256 * i];
  }
  __syncthreads();
  const int col = t & 127;
  const int half = t >> 7;
  float acc[8] = {0.f, 0.f, 0.f, 0.f, 0.f, 0.f, 0.f, 0.f};
  const float* wrow = Wr + col * DD;
  for (int k = 0; k < DD; k += 4) {
    const float4 w = *(const float4*)(wrow + k);
#pragma unroll
    for (int m = 0; m < 8; ++m) {
      const float4 hv = *(const float4*)(&hs[(half + 2 * m) * DD + k]);
      acc[m] += w.x * hv.x + w.y * hv.y + w.z * hv.z + w.w * hv.w;
    }
  }
  const int b = rbase >> 11;           // row / N
  const int j0 = rbase & (NN - 1);
  const int head = col >> 5, d = col & 31;
  short* vdst = Vt + ((size_t)((b * HH + head) * HD + d)) * NN + j0;
#pragma unroll
  for (int m = 0; m < 8; ++m) vdst[half + 2 * m] = f2bf(acc[m]);
}

// K1b: expsr[bh][j] = exp(leaky(fr) @ ar); rk/rq[bh][j][4]
__global__ __launch_bounds__(256) void k1b_aux(
    const short* __restrict__ Vt, const float* __restrict__ rh,
    const float* __restrict__ ar, const float* __restrict__ Wrs,
    const float* __restrict__ Wrt,
    float* __restrict__ expsr, float* __restrict__ rko, float* __restrict__ rqo) {
  const int gid = blockIdx.x * 256 + threadIdx.x;  // 0 .. B*N-1
  const int b = gid >> 11;
  const int j = gid & (NN - 1);
#pragma unroll
  for (int hh = 0; hh < HH; ++hh) {
    const short* vp = Vt + ((size_t)((b * HH + hh) * HD)) * NN + j;
    float s = 0.f;
#pragma unroll
    for (int d = 0; d < HD; ++d) {
      float v = bf2f(vp[(size_t)d * NN]);
      v = v > 0.f ? v : 0.01f * v;
      s += v * ar[d];
    }
    expsr[(b * HH + hh) * NN + j] = __expf(s);
  }
  const float4 r = *(const float4*)(rh + (size_t)gid * RLL);
#pragma unroll
  for (int hh = 0; hh < HH; ++hh) {
    float* kp = rko + ((size_t)((b * HH + hh) * NN + j)) * RLL;
    float* qp = rqo + ((size_t)((b * HH + hh) * NN + j)) * RLL;
#pragma unroll
    for (int rr = 0; rr < RLL; ++rr) {
      const float4 ws = *(const float4*)(Wrs + (hh * RLL + rr) * RLL);
      const float4 wt = *(const float4*)(Wrt + (hh * RLL + rr) * RLL);
      kp[rr] = r.x * ws.x + r.y * ws.y + r.z * ws.z + r.w * ws.w;
      qp[rr] = r.x * wt.x + r.y * wt.y + r.z * wt.z + r.w * wt.w;
    }
  }
}

// K2: flash attention. One wave = 16 q-rows; numerator p = expsr_j * exp(rk_i . rq_j)
// computed per-lane directly in the MFMA A-fragment layout (row = lane&15,
// k = (lane>>4)*8 + i). B-frag = contiguous 16B load from transposed Vt.
__global__ __launch_bounds__(256) void k2_attn(
    const short* __restrict__ Vt, const float* __restrict__ expsr,
    const float* __restrict__ rk, const float* __restrict__ rq,
    float* __restrict__ h_sa) {
  __shared__ float rq_s[NN * RLL];  // 32 KB
  __shared__ float es_s[NN];        // 8 KB
  const int t = threadIdx.x;
  const int bh = blockIdx.y;
  {
    const float4* src = (const float4*)(rq + (size_t)bh * NN * RLL);
    float4* dst = (float4*)rq_s;
#pragma unroll
    for (int i = 0; i < 8; ++i) dst[t + 256 * i] = src[t + 256 * i];
    const float4* esrc = (const float4*)(expsr + (size_t)bh * NN);
    float4* edst = (float4*)es_s;
#pragma unroll
    for (int i = 0; i < 2; ++i) edst[t + 256 * i] = esrc[t + 256 * i];
  }
  __syncthreads();
  const int wave = t >> 6, lane = t & 63;
  const int ibase = blockIdx.x * 64 + wave * 16;
  const int arow = lane & 15;        // A-frag row / C-frag col
  const int g = lane >> 4;           // lane group -> k-slice
  const float4 myrk = *(const float4*)(rk + ((size_t)bh * NN + ibase + arow) * RLL);
  f32x4 acc0 = {0.f, 0.f, 0.f, 0.f};
  f32x4 acc1 = {0.f, 0.f, 0.f, 0.f};
  float lsum = 0.f;
  const short* vtb = Vt + (size_t)bh * HD * NN;
  for (int jt = 0; jt < NN; jt += 32) {
    const int j0 = jt + g * 8;
    const float4 e0 = *(const float4*)(&es_s[j0]);
    const float4 e1 = *(const float4*)(&es_s[j0 + 4]);
    const float ev[8] = {e0.x, e0.y, e0.z, e0.w, e1.x, e1.y, e1.z, e1.w};
    short8 afrag;
#pragma unroll
    for (int i = 0; i < 8; ++i) {
      const float4 q = *(const float4*)(&rq_s[(j0 + i) * RLL]);
      const float e = myrk.x * q.x + myrk.y * q.y + myrk.z * q.z + myrk.w * q.w;
      const float p = __expf(e) * ev[i];
      lsum += p;
      afrag[i] = f2bf(p);
    }
    const short8 b0 = *(const short8*)(vtb + (size_t)arow * NN + j0);
    const short8 b1 = *(const short8*)(vtb + (size_t)(16 + arow) * NN + j0);
    acc0 = __builtin_amdgcn_mfma_f32_16x16x32_bf16(afrag, b0, acc0, 0, 0, 0);
    acc1 = __builtin_amdgcn_mfma_f32_16x16x32_bf16(afrag, b1, acc1, 0, 0, 0);
  }
  lsum += __shfl_xor(lsum, 16);
  lsum += __shfl_xor(lsum, 32);  // every lane: full row-sum for row (lane&15)
  const int b = bh >> 2, head = bh & 3;
  float* base = h_sa + ((size_t)b * NN + ibase) * DD + head * HD;
#pragma unroll
  for (int reg = 0; reg < 4; ++reg) {
    const int r = g * 4 + reg;                 // C row = (lane>>4)*4 + reg
    const float linv = 1.f / __shfl(lsum, r);  // row-sum lives in lane r
    base[(size_t)r * DD + arow] = acc0[reg] * linv;
    base[(size_t)r * DD + 16 + arow] = acc1[reg] * linv;
  }
}

// K3: x = h + h_sa @ Wf.T, then LayerNorm over D, fused (block covers all 128 cols)
__global__ __launch_bounds__(256) void k3_final(
    const float* __restrict__ h_sa, const float* __restrict__ h,
    const float* __restrict__ Wf, const float* __restrict__ ln_g,
    const float* __restrict__ ln_b, float* __restrict__ out) {
  __shared__ float ss[16 * DD];
  __shared__ float2 red[4][8];
  const int t = threadIdx.x;
  const int rbase = blockIdx.x * 16;
  {
    const float4* src = (const float4*)(h_sa + (size_t)rbase * DD);
    float4* dst = (float4*)ss;
#pragma unroll
    for (int i = 0; i < 2; ++i) dst[t + 256 * i] = src[t + 256 * i];
  }
  __syncthreads();
  const int col = t & 127;
  const int half = t >> 7;
  const int wave = t >> 6;
  float acc[8] = {0.f, 0.f, 0.f, 0.f, 0.f, 0.f, 0.f, 0.f};
  const float* wrow = Wf + col * DD;
  for (int k = 0; k < DD; k += 4) {
    const float4 w = *(const float4*)(wrow + k);
#pragma unroll
    for (int m = 0; m < 8; ++m) {
      const float4 hv = *(const float4*)(&ss[(half + 2 * m) * DD + k]);
      acc[m] += w.x * hv.x + w.y * hv.y + w.z * hv.z + w.w * hv.w;
    }
  }
  float xv[8];
#pragma unroll
  for (int m = 0; m < 8; ++m)
    xv[m] = h[((size_t)rbase + half + 2 * m) * DD + col] + acc[m];
  float s[8], q[8];
#pragma unroll
  for (int m = 0; m < 8; ++m) {
    float sv = xv[m], qv = xv[m] * xv[m];
#pragma unroll
    for (int o = 1; o < 64; o <<= 1) {
      sv += __shfl_xor(sv, o);
      qv += __shfl_xor(qv, o);
    }
    s[m] = sv;
    q[m] = qv;
  }
  if ((t & 63) == 0) {
#pragma unroll
    for (int m = 0; m < 8; ++m) red[wave][m] = make_float2(s[m], q[m]);
  }
  __syncthreads();
  const float gc = ln_g[col], bc = ln_b[col];
#pragma unroll
  for (int m = 0; m < 8; ++m) {
    const float2 a = red[wave][m];
    const float2 bb = red[wave ^ 1][m];
    const float mu = (a.x + bb.x) * (1.f / 128.f);
    const float var = (a.y + bb.y) * (1.f / 128.f) - mu * mu;
    const float inv = rsqrtf(var + 1e-5f);
    out[((size_t)rbase + half + 2 * m) * DD + col] = (xv[m] - mu) * inv * gc + bc;
  }
}

extern "C" void kernel_launch(void* const* d_in, const int* in_sizes, int n_in,
                              void* d_out, int out_size, void* d_ws, size_t ws_size,
                              hipStream_t stream) {
  (void)in_sizes; (void)n_in; (void)out_size; (void)ws_size;
  const float* h    = (const float*)d_in[0];
  const float* rh   = (const float*)d_in[1];
  // d_in[2] = Wl, d_in[4] = al: dead (softmax shift invariance)
  const float* Wr   = (const float*)d_in[3];
  const float* ar   = (const float*)d_in[5];
  const float* Wrs  = (const float*)d_in[6];
  const float* Wrt  = (const float*)d_in[7];
  const float* Wf   = (const float*)d_in[8];
  const float* ln_g = (const float*)d_in[9];
  const float* ln_b = (const float*)d_in[10];
  float* out = (float*)d_out;

  char* ws = (char*)d_ws;
  short* Vt    = (short*)(ws);                                   // 2 MB
  float* expsr = (float*)(ws + (2u << 20));                      // 128 KB
  float* rk    = (float*)(ws + (2u << 20) + (128u << 10));       // 512 KB
  float* rq    = (float*)(ws + (2u << 20) + (640u << 10));       // 512 KB
  float* h_sa  = (float*)(ws + (2u << 20) + (1152u << 10));      // 4 MB

  hipLaunchKernelGGL(k1_proj, dim3(BB * NN / 16), dim3(256), 0, stream, h, Wr, Vt);
  hipLaunchKernelGGL(k1b_aux, dim3(BB * NN / 256), dim3(256), 0, stream,
                     Vt, rh, ar, Wrs, Wrt, expsr, rk, rq);
  hipLaunchKernelGGL(k2_attn, dim3(NN / 64, BH), dim3(256), 0, stream,
                     Vt, expsr, rk, rq, h_sa);
  hipLaunchKernelGGL(k3_final, dim3(BB * NN / 16), dim3(256), 0, stream,
                     h_sa, h, Wf, ln_g, ln_b, out);
}

// Round 3
// 110.388 us; speedup vs baseline: 1.2936x; 1.2936x over previous
//
#include <hip/hip_runtime.h>

#define NN 2048
#define DD 128
#define HH 4

typedef __attribute__((ext_vector_type(8))) short short8;
typedef __attribute__((ext_vector_type(16))) float f32x16;
typedef __attribute__((ext_vector_type(4))) unsigned uint4v;

static __device__ __forceinline__ unsigned cvtpk(float lo, float hi) {
  unsigned r;
  asm("v_cvt_pk_bf16_f32 %0, %1, %2" : "=v"(r) : "v"(lo), "v"(hi));
  return r;
}
static __device__ __forceinline__ void plswap(unsigned& a, unsigned& b) {
  asm("v_permlane32_swap_b32 %0, %1" : "+v"(a), "+v"(b));
}
static __device__ __forceinline__ float dot4(float4 a, float4 b) {
  return a.x * b.x + a.y * b.y + a.z * b.z + a.w * b.w;
}

// K1: Vt[b*128 + d][j] = (Wr @ h^T) in bf16, fused sr[b,h,j] = leaky(fr).ar
// 32x32x16 MFMA; A = Wr rows (LDS bf16 swizzled), B = h rows (LDS bf16 swizzled).
__global__ __launch_bounds__(256) void k1_proj(
    const float* __restrict__ h, const float* __restrict__ Wr,
    const float* __restrict__ ar, short* __restrict__ Vt,
    float* __restrict__ sr) {
  __shared__ short wr_s[DD * DD];   // 32 KB, 16B-chunk c of row d stored at c^(d&7)
  __shared__ short h_s[32 * DD];    // 8 KB, same swizzle per row j
  const int t = threadIdx.x;
  const int lane = t & 63, wv = t >> 6;
  const int b = blockIdx.x >> 6;
  const int j0 = (blockIdx.x & 63) * 32;
  {
    const int d = t >> 1, c0 = (t & 1) * 8;
    const float* src = Wr + d * DD + c0 * 8;
#pragma unroll
    for (int c = 0; c < 8; ++c) {
      const float4 x = *(const float4*)(src + c * 8);
      const float4 y = *(const float4*)(src + c * 8 + 4);
      uint4v v = {cvtpk(x.x, x.y), cvtpk(x.z, x.w), cvtpk(y.x, y.y), cvtpk(y.z, y.w)};
      *(uint4v*)(wr_s + d * DD + (((c0 + c) ^ (d & 7)) << 3)) = v;
    }
  }
  {
    const int j = t >> 3, c0 = (t & 7) * 2;
    const float* src = h + (size_t)(b * NN + j0 + j) * DD + c0 * 8;
#pragma unroll
    for (int c = 0; c < 2; ++c) {
      const float4 x = *(const float4*)(src + c * 8);
      const float4 y = *(const float4*)(src + c * 8 + 4);
      uint4v v = {cvtpk(x.x, x.y), cvtpk(x.z, x.w), cvtpk(y.x, y.y), cvtpk(y.z, y.w)};
      *(uint4v*)(h_s + j * DD + (((c0 + c) ^ (j & 7)) << 3)) = v;
    }
  }
  __syncthreads();
  const int l31 = lane & 31, kg = lane >> 5;
  const int rowA = wv * 32 + l31;
  f32x16 acc = {0, 0, 0, 0, 0, 0, 0, 0, 0, 0, 0, 0, 0, 0, 0, 0};
#pragma unroll
  for (int ks = 0; ks < 8; ++ks) {
    const int ch = ks * 2 + kg;
    const short8 a = *(const short8*)(wr_s + rowA * DD + ((ch ^ (rowA & 7)) << 3));
    const short8 bb = *(const short8*)(h_s + l31 * DD + ((ch ^ (l31 & 7)) << 3));
    acc = __builtin_amdgcn_mfma_f32_32x32x16_bf16(a, bb, acc, 0, 0, 0);
  }
  const int hi4 = kg * 4;
  float4 arv[4];
#pragma unroll
  for (int q = 0; q < 4; ++q) arv[q] = *(const float4*)(ar + q * 8 + hi4);
  float srp = 0.f;
  short* vrow = Vt + (size_t)(b * DD + wv * 32) * NN + j0 + l31;
#pragma unroll
  for (int r = 0; r < 16; ++r) {
    const int dloc = (r & 3) + 8 * (r >> 2) + hi4;
    const float v = acc[r];
    const float lv = v > 0.f ? v : 0.01f * v;
    const float arc =
        (r & 3) == 0 ? arv[r >> 2].x : (r & 3) == 1 ? arv[r >> 2].y : (r & 3) == 2 ? arv[r >> 2].z : arv[r >> 2].w;
    srp += lv * arc;
    vrow[(size_t)dloc * NN] = (short)cvtpk(v, v);
  }
  srp += __shfl_xor(srp, 32);
  if (lane < 32) sr[(b * HH + wv) * NN + j0 + lane] = srp;
}

// K2: flash attention via rank-5 score MFMA (p = exp(rk_i.rq_j + sr_j)) and
// in-register C->B repack (cvt_pk + permlane32_swap), PV MFMA from Vt.
__global__ __launch_bounds__(256) void k2_attn(
    const float* __restrict__ rh, const float* __restrict__ Wrs,
    const float* __restrict__ Wrt, const float* __restrict__ sr,
    const short* __restrict__ Vt, float* __restrict__ h_sa) {
  __shared__ short rqsr_s[NN * 8];  // [j] = {rq0..rq3, sr, 0,0,0} bf16, 32 KB
  __shared__ float4 redA[2][4][64];
  __shared__ float redL[2][64];
  __shared__ float tbuf[2][32 * 36];
  const int t = threadIdx.x;
  const int lane = t & 63, wv = t >> 6;
  const int strip = wv >> 1, jh = wv & 1;
  const int bh = blockIdx.y, b = bh >> 2, head = bh & 3;
  const int i0 = blockIdx.x * 64 + strip * 32;
  const int l31 = lane & 31, kg = lane >> 5;

  const float4 wt0 = *(const float4*)(Wrt + (head * 4 + 0) * 4);
  const float4 wt1 = *(const float4*)(Wrt + (head * 4 + 1) * 4);
  const float4 wt2 = *(const float4*)(Wrt + (head * 4 + 2) * 4);
  const float4 wt3 = *(const float4*)(Wrt + (head * 4 + 3) * 4);
#pragma unroll
  for (int q = 0; q < 8; ++q) {
    const int j = q * 256 + t;
    const float4 r4 = *(const float4*)(rh + (size_t)(b * NN + j) * 4);
    const float srj = sr[bh * NN + j];
    uint4v v = {cvtpk(dot4(r4, wt0), dot4(r4, wt1)), cvtpk(dot4(r4, wt2), dot4(r4, wt3)),
                cvtpk(srj, 0.f), 0u};
    *(uint4v*)(rqsr_s + j * 8) = v;
  }
  uint4v bk = {0u, 0u, 0u, 0u};
  if (lane < 32) {
    const float4 r4 = *(const float4*)(rh + (size_t)(b * NN + i0 + l31) * 4);
    const float4 ws0 = *(const float4*)(Wrs + (head * 4 + 0) * 4);
    const float4 ws1 = *(const float4*)(Wrs + (head * 4 + 1) * 4);
    const float4 ws2 = *(const float4*)(Wrs + (head * 4 + 2) * 4);
    const float4 ws3 = *(const float4*)(Wrs + (head * 4 + 3) * 4);
    bk[0] = cvtpk(dot4(r4, ws0), dot4(r4, ws1));
    bk[1] = cvtpk(dot4(r4, ws2), dot4(r4, ws3));
    bk[2] = cvtpk(1.f, 0.f);
  }
  const short8 bkf = __builtin_bit_cast(short8, bk);
  __syncthreads();

  const short* vtb = Vt + (size_t)bh * 32 * NN + (size_t)l31 * NN;
  const f32x16 zero = {0, 0, 0, 0, 0, 0, 0, 0, 0, 0, 0, 0, 0, 0, 0, 0};
  f32x16 acc = zero;
  float lsum = 0.f;
  const int jbase = jh * 1024;
#pragma unroll 2
  for (int jj = 0; jj < 1024; jj += 32) {
    const int j0w = jbase + jj;
    uint4v aqu = *(const uint4v*)(rqsr_s + (j0w + l31) * 8);
    if (lane >= 32) { aqu[0] = 0u; aqu[1] = 0u; aqu[2] = 0u; aqu[3] = 0u; }
    const short8 aq = __builtin_bit_cast(short8, aqu);
    const f32x16 sc = __builtin_amdgcn_mfma_f32_32x32x16_bf16(aq, bkf, zero, 0, 0, 0);
    float e[16];
#pragma unroll
    for (int r = 0; r < 16; ++r) {
      e[r] = __expf(sc[r]);
      lsum += e[r];
    }
    unsigned d0 = cvtpk(e[0], e[1]), d1 = cvtpk(e[2], e[3]);
    unsigned d2 = cvtpk(e[4], e[5]), d3 = cvtpk(e[6], e[7]);
    unsigned d4 = cvtpk(e[8], e[9]), d5 = cvtpk(e[10], e[11]);
    unsigned d6 = cvtpk(e[12], e[13]), d7 = cvtpk(e[14], e[15]);
    plswap(d0, d2);
    plswap(d1, d3);
    plswap(d4, d6);
    plswap(d5, d7);
    uint4v b0u = {d0, d1, d2, d3};
    uint4v b1u = {d4, d5, d6, d7};
    const short8 p0 = __builtin_bit_cast(short8, b0u);
    const short8 p1 = __builtin_bit_cast(short8, b1u);
    const short8 va0 = *(const short8*)(vtb + j0w + kg * 8);
    const short8 va1 = *(const short8*)(vtb + j0w + 16 + kg * 8);
    acc = __builtin_amdgcn_mfma_f32_32x32x16_bf16(va0, p0, acc, 0, 0, 0);
    acc = __builtin_amdgcn_mfma_f32_32x32x16_bf16(va1, p1, acc, 0, 0, 0);
  }
  lsum += __shfl_xor(lsum, 32);
  if (jh == 1) {
#pragma unroll
    for (int rg = 0; rg < 4; ++rg)
      redA[strip][rg][lane] = make_float4(acc[rg * 4], acc[rg * 4 + 1], acc[rg * 4 + 2], acc[rg * 4 + 3]);
    redL[strip][lane] = lsum;
  }
  __syncthreads();
  if (jh == 0) {
#pragma unroll
    for (int rg = 0; rg < 4; ++rg) {
      const float4 o = redA[strip][rg][lane];
      acc[rg * 4] += o.x;
      acc[rg * 4 + 1] += o.y;
      acc[rg * 4 + 2] += o.z;
      acc[rg * 4 + 3] += o.w;
    }
    lsum += redL[strip][lane];
    const float linv = 1.f / lsum;
    const int hi4 = kg * 4;
#pragma unroll
    for (int r = 0; r < 16; ++r) {
      const int dloc = (r & 3) + 8 * (r >> 2) + hi4;
      tbuf[strip][l31 * 36 + dloc] = acc[r] * linv;
    }
  }
  __syncthreads();
  if (jh == 0) {
    const int il = lane >> 1, hf = lane & 1;
    const float* tp = &tbuf[strip][il * 36 + hf * 16];
    float* op = h_sa + (size_t)(b * NN + i0 + il) * DD + head * 32 + hf * 16;
#pragma unroll
    for (int qq = 0; qq < 4; ++qq) *(float4*)(op + qq * 4) = *(const float4*)(tp + qq * 4);
  }
}

// K3: fh = h_sa @ Wf^T (32x32x16 MFMA, on-the-fly bf16), +h residual, fused LN.
__global__ __launch_bounds__(256) void k3_final(
    const float* __restrict__ h_sa, const float* __restrict__ h,
    const float* __restrict__ Wf, const float* __restrict__ ln_g,
    const float* __restrict__ ln_b, float* __restrict__ out) {
  __shared__ float2 redln[4][32];
  __shared__ float2 fin[32];
  const int t = threadIdx.x, lane = t & 63, wv = t >> 6;
  const int l31 = lane & 31, kg = lane >> 5;
  const int rbase = blockIdx.x * 32, c0 = wv * 32;
  f32x16 acc = {0, 0, 0, 0, 0, 0, 0, 0, 0, 0, 0, 0, 0, 0, 0, 0};
  const float* ap0 = h_sa + (size_t)(rbase + l31) * DD;
  const float* bp0 = Wf + (size_t)(c0 + l31) * DD;
#pragma unroll
  for (int ks = 0; ks < 8; ++ks) {
    const int ko = ks * 16 + kg * 8;
    const float4 a0 = *(const float4*)(ap0 + ko);
    const float4 a1 = *(const float4*)(ap0 + ko + 4);
    const float4 b0 = *(const float4*)(bp0 + ko);
    const float4 b1 = *(const float4*)(bp0 + ko + 4);
    uint4v au = {cvtpk(a0.x, a0.y), cvtpk(a0.z, a0.w), cvtpk(a1.x, a1.y), cvtpk(a1.z, a1.w)};
    uint4v bu = {cvtpk(b0.x, b0.y), cvtpk(b0.z, b0.w), cvtpk(b1.x, b1.y), cvtpk(b1.z, b1.w)};
    acc = __builtin_amdgcn_mfma_f32_32x32x16_bf16(__builtin_bit_cast(short8, au),
                                                  __builtin_bit_cast(short8, bu), acc, 0, 0, 0);
  }
  const int hi4 = kg * 4;
  float x[16];
#pragma unroll
  for (int r = 0; r < 16; ++r) {
    const int row = (r & 3) + 8 * (r >> 2) + hi4;
    x[r] = acc[r] + h[(size_t)(rbase + row) * DD + c0 + l31];
    float a = x[r], bsq = x[r] * x[r];
#pragma unroll
    for (int o = 1; o < 32; o <<= 1) {
      a += __shfl_xor(a, o);
      bsq += __shfl_xor(bsq, o);
    }
    if (l31 == 0) redln[wv][row] = make_float2(a, bsq);
  }
  __syncthreads();
  if (wv == 0 && lane < 32) {
    float ss = 0.f, qq = 0.f;
#pragma unroll
    for (int w = 0; w < 4; ++w) {
      const float2 p = redln[w][lane];
      ss += p.x;
      qq += p.y;
    }
    const float mu = ss * (1.f / 128.f);
    const float var = qq * (1.f / 128.f) - mu * mu;
    fin[lane] = make_float2(mu, rsqrtf(var + 1e-5f));
  }
  __syncthreads();
  const float g = ln_g[c0 + l31], bb = ln_b[c0 + l31];
#pragma unroll
  for (int r = 0; r < 16; ++r) {
    const int row = (r & 3) + 8 * (r >> 2) + hi4;
    const float2 f = fin[row];
    out[(size_t)(rbase + row) * DD + c0 + l31] = (x[r] - f.x) * f.y * g + bb;
  }
}

extern "C" void kernel_launch(void* const* d_in, const int* in_sizes, int n_in,
                              void* d_out, int out_size, void* d_ws, size_t ws_size,
                              hipStream_t stream) {
  (void)in_sizes; (void)n_in; (void)out_size; (void)ws_size;
  const float* h = (const float*)d_in[0];
  const float* rh = (const float*)d_in[1];
  // d_in[2]=Wl, d_in[4]=al: dead (softmax shift invariance)
  const float* Wr = (const float*)d_in[3];
  const float* ar = (const float*)d_in[5];
  const float* Wrs = (const float*)d_in[6];
  const float* Wrt = (const float*)d_in[7];
  const float* Wf = (const float*)d_in[8];
  const float* ln_g = (const float*)d_in[9];
  const float* ln_b = (const float*)d_in[10];
  float* out = (float*)d_out;

  char* ws = (char*)d_ws;
  short* Vt = (short*)ws;                                 // 2 MB
  float* sr = (float*)(ws + (2u << 20));                  // 128 KB
  float* h_sa = (float*)(ws + (2u << 20) + (256u << 10)); // 4 MB

  hipLaunchKernelGGL(k1_proj, dim3(256), dim3(256), 0, stream, h, Wr, ar, Vt, sr);
  hipLaunchKernelGGL(k2_attn, dim3(32, 16), dim3(256), 0, stream, rh, Wrs, Wrt, sr, Vt, h_sa);
  hipLaunchKernelGGL(k3_final, dim3(256), dim3(256), 0, stream, h_sa, h, Wf, ln_g, ln_b, out);
}